// Round 7
// baseline (651.276 us; speedup 1.0000x reference)
//
#include <hip/hip_runtime.h>

#define Nn 100000
#define Ee 800000
#define HC 128
#define HID 32
#define NHD 4
#define EDIM 16
#define Gg 256
#define NOUT 2
#define SLOPE 0.2f
#define BN_EPS 1e-5f
#define SCHUNK 1024
#define NSB 98     // ceil(Nn/SCHUNK)
#define NPB 8      // nodes per aggregate block (1 wave/node, 512 thr)
#define NBAG 12500 // ceil(Nn/NPB) aggregate blocks / BN slots

typedef unsigned int u32;
typedef unsigned short u16;
typedef short v8s __attribute__((ext_vector_type(8)));
typedef float v4f __attribute__((ext_vector_type(4)));

union PkAB { u32 u[4]; v8s v; };

__device__ __forceinline__ float bflo(u32 u){ return __uint_as_float(u << 16); }
__device__ __forceinline__ float bfhi(u32 u){ return __uint_as_float(u & 0xFFFF0000u); }

__device__ __forceinline__ u32 bf16rne(float x)
{
  u32 b = __float_as_uint(x);
  return (b + 0x7FFFu + ((b >> 16) & 1u)) >> 16;
}
__device__ __forceinline__ u32 packsplit(float x)
{
  u32 hb = bf16rne(x);
  float hf = __uint_as_float(hb << 16);
  u32 lb = bf16rne(x - hf);
  return hb | (lb << 16);
}
__device__ __forceinline__ void split2(float f, u32& hb, u32& lb)
{
  hb = bf16rne(f);
  lb = bf16rne(f - __uint_as_float(hb << 16));
}

__device__ __forceinline__ int lbound(const int* __restrict__ a, int n, int key)
{
  int lo = 0, hi = n;
  while (lo < hi) {
    int mid = (lo + hi) >> 1;
    if (a[mid] < key) lo = mid + 1; else hi = mid;
  }
  return lo;
}

// ---- tiny weight precompute: Kmat[16][12], kb[12]; also graph-boundary gb ----
__global__ void compute_K(const float* __restrict__ efcW, const float* __restrict__ efcb,
                          const float* __restrict__ linE, const float* __restrict__ attE,
                          float* __restrict__ Kmat, float* __restrict__ kb,
                          const int* __restrict__ batch, int* __restrict__ gb)
{
  __shared__ float Msh[384];
  int t = threadIdx.x;
  if (t <= Gg) gb[t] = lbound(batch, Nn, t);   // independent of the rest
  if (t < 384) {
    int l = t >> 7, j = (t >> 2) & 31, h = t & 3;
    float m = 0.f;
    for (int c = 0; c < 32; ++c)
      m += linE[(l*32 + j)*128 + h*32 + c] * attE[(l*4 + h)*32 + c];
    Msh[l*128 + j*4 + h] = m;
  }
  __syncthreads();
  if (t < 192) {
    int k = t / 12, col = t % 12, l = col >> 2, h = col & 3;
    float acc = 0.f;
    for (int j = 0; j < 32; ++j)
      acc += efcW[k*32 + j] * Msh[l*128 + j*4 + h];
    Kmat[k*12 + col] = acc;
  } else if (t < 204) {
    int col = t - 192, l = col >> 2, h = col & 3;
    float acc = 0.f;
    for (int j = 0; j < 32; ++j)
      acc += efcb[j] * Msh[l*128 + j*4 + h];
    kb[col] = acc;
  }
}

// ---- W -> split-bf16 MFMA B-fragment layout (once) ----
__global__ void w_split(const float* __restrict__ Wall, u32* __restrict__ Wf)
{
  int tid = blockIdx.x * 256 + threadIdx.x;
  if (tid >= 3*HC*HC) return;
  int l = tid / (HC*HC);
  int rem = tid - l*HC*HC;
  int k = rem >> 7, n = rem & 127;
  u32 p = packsplit(Wall[tid]);
  int nt = n >> 4, col = n & 15;
  int ks = k >> 5, kin = k & 31, q = kin >> 3, j = kin & 7;
  int half = j >> 2, j4 = j & 3;
  int idx = ((((l*8 + nt)*4 + ks)*2 + half)*64 + q*16 + col)*4 + j4;
  Wf[idx] = p;
}

// ---- CSR build ----
__global__ void k_hist(const int* __restrict__ dst, int* __restrict__ deg)
{
  int e = blockIdx.x * 256 + threadIdx.x;
  if (e < Ee) atomicAdd(&deg[dst[e]], 1);
}

__global__ void k_bsum(const int* __restrict__ deg, int* __restrict__ bsum)
{
  __shared__ int sh[256];
  int b = blockIdx.x, t = threadIdx.x;
  int s = 0;
  for (int i = t; i < SCHUNK; i += 256) {
    int idx = b*SCHUNK + i;
    if (idx < Nn) s += deg[idx];
  }
  sh[t] = s; __syncthreads();
  for (int o = 128; o; o >>= 1) { if (t < o) sh[t] += sh[t+o]; __syncthreads(); }
  if (!t) bsum[b] = sh[0];
}

__global__ void k_mid(const int* __restrict__ bsum, int* __restrict__ bpre, int* __restrict__ rowp)
{
  __shared__ int sh[NSB];
  int t = threadIdx.x;
  if (t < NSB) sh[t] = bsum[t];
  __syncthreads();
  if (!t) {
    int run = 0;
    for (int i = 0; i < NSB; ++i) { int v = sh[i]; sh[i] = run; run += v; }
    rowp[Nn] = run;
  }
  __syncthreads();
  if (t < NSB) bpre[t] = sh[t];
}

__global__ void k_scan(const int* __restrict__ deg, const int* __restrict__ bpre, int* __restrict__ rowp)
{
  __shared__ int sh[SCHUNK];
  int b = blockIdx.x, t = threadIdx.x;
  for (int i = t; i < SCHUNK; i += 256) {
    int idx = b*SCHUNK + i;
    sh[i] = (idx < Nn) ? deg[idx] : 0;
  }
  __syncthreads();
  if (!t) {
    int run = 0;
    for (int i = 0; i < SCHUNK; ++i) { int v = sh[i]; sh[i] = run; run += v; }
  }
  __syncthreads();
  int base = bpre[b];
  for (int i = t; i < SCHUNK; i += 256) {
    int idx = b*SCHUNK + i;
    if (idx < Nn) rowp[idx] = sh[i] + base;
  }
}

// scatter only an 8-byte {edge id, src} pair to the dst-sorted position.
__global__ void k_mkperm(const int* __restrict__ src, const int* __restrict__ dst,
                         const int* __restrict__ rowp, int* __restrict__ fill,
                         uint2* __restrict__ eord)
{
  int e = blockIdx.x * 256 + threadIdx.x;
  if (e >= Ee) return;
  int d = dst[e];
  int pos = rowp[d] + atomicAdd(&fill[d], 1);
  eord[pos] = make_uint2((u32)e, (u32)src[e]);
}

// QUAD-COOPERATIVE edge precompute: 4 lanes per edge read the 64-B eattr
// line coalesced; shfl-reduce the 16x12 matvec; lanes write SoA planes
// coalesced. recS[pos]=src ; recE[l][pos] = uint2{ep0|ep1<<16, ep2|ep3<<16}.
__global__ __launch_bounds__(256) void k_fillpre2(const uint2* __restrict__ eord,
                           const float* __restrict__ eattr,
                           const float* __restrict__ Kmat, const float* __restrict__ kb,
                           u32* __restrict__ recS, uint2* __restrict__ recE)
{
  int t = threadIdx.x;
  int qg = t >> 2, r = t & 3;
  int pos = blockIdx.x * 64 + qg;
  if (pos >= Ee) return;
  uint2 es = eord[pos];           // broadcast within quad
  int e = (int)es.x;
  float4 ea = *(const float4*)(eattr + (size_t)e * EDIM + r*4);  // quad covers one 64B line
  float part[12];
  #pragma unroll
  for (int col = 0; col < 12; ++col) {
    part[col] = ea.x * Kmat[(r*4+0)*12 + col]
              + ea.y * Kmat[(r*4+1)*12 + col]
              + ea.z * Kmat[(r*4+2)*12 + col]
              + ea.w * Kmat[(r*4+3)*12 + col];
  }
  #pragma unroll
  for (int col = 0; col < 12; ++col) {
    part[col] += __shfl_xor(part[col], 1);
    part[col] += __shfl_xor(part[col], 2);
    part[col] += kb[col];
  }
  if (r < 3) {
    uint2 w;
    w.x = bf16rne(part[4*r+0]) | (bf16rne(part[4*r+1]) << 16);
    w.y = bf16rne(part[4*r+2]) | (bf16rne(part[4*r+3]) << 16);
    recE[(size_t)r*Ee + pos] = w;
  } else {
    recS[pos] = es.y;
  }
}

// ---- MFMA GEMM, 64-row blocks; B ks-slice staged in 16 KB LDS;
// mode 0: A = raw fp32 x rows (layer 0; split inline, no split_x pass)
// mode 1: A = packed split-bf16 rows + BN+ReLU of prev layer at A-load
// C as bf16; attn dots fused; as_/ad_ node-major.
__global__ __launch_bounds__(256, 4) void gemm_mfma(const u32* __restrict__ Apk,
                                                    const u32* __restrict__ Wf,
                                                    u16* __restrict__ C2,
                                                    const float* __restrict__ aS,
                                                    const float* __restrict__ aD,
                                                    float* __restrict__ as_,
                                                    float* __restrict__ ad_,
                                                    const float* __restrict__ scb,
                                                    const float* __restrict__ shb,
                                                    int mode)
{
  __shared__ uint4 Bsh[1024];   // 16 KB: [nt(8)][half(2)][lane(64)]
  int t = threadIdx.x;
  int w = t >> 6, lane = t & 63;
  int col = lane & 15, q = lane >> 4;
  int rbase = blockIdx.x * 64 + w * 16;

  v4f acc[8];
  #pragma unroll
  for (int nt = 0; nt < 8; ++nt) acc[nt] = (v4f){0.f, 0.f, 0.f, 0.f};

  const uint4* Wf4 = (const uint4*)Wf;

  int ar = rbase + col;
  if (ar >= Nn) ar = Nn - 1;
  const uint4* pa = (const uint4*)(Apk + (size_t)ar*HC);
  uint4 ra[8];
  #pragma unroll
  for (int ks = 0; ks < 4; ++ks) {
    ra[2*ks]   = pa[ks*8 + q*2];
    ra[2*ks+1] = pa[ks*8 + q*2 + 1];
  }

  for (int ks = 0; ks < 4; ++ks) {
    // stage B ks-slice: 1024 uint4 (8 nt x 2 half x 64 lane)
    #pragma unroll
    for (int i = 0; i < 4; ++i) {
      int u = t + i*256;
      int nt = u >> 7, rem = u & 127;
      Bsh[u] = Wf4[((nt*4 + ks)*2 + (rem >> 6))*64 + (rem & 63)];
    }
    __syncthreads();

    PkAB Ah, Al;
    int cb = ks*32 + q*8;
    uint4 r0 = ra[2*ks], r1 = ra[2*ks+1];
    float f0, f1, f2, f3, f4, f5, f6, f7;
    if (mode == 0) {
      // raw fp32 x: uint4 lanes are float bits
      f0 = __uint_as_float(r0.x); f1 = __uint_as_float(r0.y);
      f2 = __uint_as_float(r0.z); f3 = __uint_as_float(r0.w);
      f4 = __uint_as_float(r1.x); f5 = __uint_as_float(r1.y);
      f6 = __uint_as_float(r1.z); f7 = __uint_as_float(r1.w);
    } else {
      float4 sc0 = *(const float4*)(scb + cb), sc1 = *(const float4*)(scb + cb + 4);
      float4 sh0 = *(const float4*)(shb + cb), sh1 = *(const float4*)(shb + cb + 4);
      f0 = fmaxf((bflo(r0.x)+bfhi(r0.x))*sc0.x + sh0.x, 0.f);
      f1 = fmaxf((bflo(r0.y)+bfhi(r0.y))*sc0.y + sh0.y, 0.f);
      f2 = fmaxf((bflo(r0.z)+bfhi(r0.z))*sc0.z + sh0.z, 0.f);
      f3 = fmaxf((bflo(r0.w)+bfhi(r0.w))*sc0.w + sh0.w, 0.f);
      f4 = fmaxf((bflo(r1.x)+bfhi(r1.x))*sc1.x + sh1.x, 0.f);
      f5 = fmaxf((bflo(r1.y)+bfhi(r1.y))*sc1.y + sh1.y, 0.f);
      f6 = fmaxf((bflo(r1.z)+bfhi(r1.z))*sc1.z + sh1.z, 0.f);
      f7 = fmaxf((bflo(r1.w)+bfhi(r1.w))*sc1.w + sh1.w, 0.f);
    }
    {
      u32 hb0,lb0,hb1,lb1,hb2,lb2,hb3,lb3,hb4,lb4,hb5,lb5,hb6,lb6,hb7,lb7;
      split2(f0,hb0,lb0); split2(f1,hb1,lb1); split2(f2,hb2,lb2); split2(f3,hb3,lb3);
      split2(f4,hb4,lb4); split2(f5,hb5,lb5); split2(f6,hb6,lb6); split2(f7,hb7,lb7);
      Ah.u[0] = hb0 | (hb1 << 16);  Al.u[0] = lb0 | (lb1 << 16);
      Ah.u[1] = hb2 | (hb3 << 16);  Al.u[1] = lb2 | (lb3 << 16);
      Ah.u[2] = hb4 | (hb5 << 16);  Al.u[2] = lb4 | (lb5 << 16);
      Ah.u[3] = hb6 | (hb7 << 16);  Al.u[3] = lb6 | (lb7 << 16);
    }
    #pragma unroll
    for (int nt = 0; nt < 8; ++nt) {
      uint4 b0 = Bsh[nt*128 + lane];
      uint4 b1 = Bsh[nt*128 + 64 + lane];
      PkAB Bh, Bl;
      Bh.u[0] = (b0.x & 0xFFFFu) | (b0.y << 16);
      Bl.u[0] = (b0.x >> 16)     | (b0.y & 0xFFFF0000u);
      Bh.u[1] = (b0.z & 0xFFFFu) | (b0.w << 16);
      Bl.u[1] = (b0.z >> 16)     | (b0.w & 0xFFFF0000u);
      Bh.u[2] = (b1.x & 0xFFFFu) | (b1.y << 16);
      Bl.u[2] = (b1.x >> 16)     | (b1.y & 0xFFFF0000u);
      Bh.u[3] = (b1.z & 0xFFFFu) | (b1.w << 16);
      Bl.u[3] = (b1.z >> 16)     | (b1.w & 0xFFFF0000u);
      acc[nt] = __builtin_amdgcn_mfma_f32_16x16x32_bf16(Ah.v, Bh.v, acc[nt], 0, 0, 0);
      acc[nt] = __builtin_amdgcn_mfma_f32_16x16x32_bf16(Ah.v, Bl.v, acc[nt], 0, 0, 0);
      acc[nt] = __builtin_amdgcn_mfma_f32_16x16x32_bf16(Al.v, Bh.v, acc[nt], 0, 0, 0);
    }
    __syncthreads();
  }

  #pragma unroll
  for (int reg = 0; reg < 4; ++reg) {
    int row = rbase + q*4 + reg;
    if (row < Nn) {
      #pragma unroll
      for (int nt = 0; nt < 8; ++nt)
        C2[(size_t)row*HC + nt*16 + col] = (u16)bf16rne(acc[nt][reg]);
    }
  }

  #pragma unroll
  for (int h = 0; h < 4; ++h) {
    float a0 = aS[32*h + col], a1 = aS[32*h + 16 + col];
    float d0 = aD[32*h + col], d1 = aD[32*h + 16 + col];
    #pragma unroll
    for (int reg = 0; reg < 4; ++reg) {
      float s1 = acc[2*h][reg]*a0 + acc[2*h+1][reg]*a1;
      float s2 = acc[2*h][reg]*d0 + acc[2*h+1][reg]*d1;
      s1 += __shfl_xor(s1, 1); s1 += __shfl_xor(s1, 2);
      s1 += __shfl_xor(s1, 4); s1 += __shfl_xor(s1, 8);
      s2 += __shfl_xor(s2, 1); s2 += __shfl_xor(s2, 2);
      s2 += __shfl_xor(s2, 4); s2 += __shfl_xor(s2, 8);
      if (col == 0) {
        int row = rbase + q*4 + reg;
        if (row < Nn) {
          as_[row*NHD + h] = s1;
          ad_[row*NHD + h] = s2;
        }
      }
    }
  }
}

// CSR aggregation, WAVE-PER-NODE: 4 edge-lanes x 16 channel-lanes per wave,
// 8 nodes (=8 waves, 512 thr) per block. Edge-lane el processes edges
// beg+el, beg+el+4, ... (2-deep unrolled); cross-edge combine via
// shfl_xor(16/32). Removes the serial-per-node straggler cost (max over 16
// node degrees per block -> max over ~deg/4 rounds per wave).
// NOTE: no min-wave VGPR clamp (R1/R5 lesson).
__global__ __launch_bounds__(512) void aggregate(const int* __restrict__ rowp,
                                                 const u32* __restrict__ recS,
                                                 const u32* __restrict__ recE,
                                                 const float* __restrict__ as_, const float* __restrict__ ad_,
                                                 int l, const u32* __restrict__ xl2,
                                                 const float* __restrict__ bias, u32* __restrict__ outp,
                                                 float* __restrict__ psum, float* __restrict__ psq)
{
  __shared__ float4 rsA[512], rsB[512], rqA[512], rqB[512];
  int t = threadIdx.x;
  int n = blockIdx.x * NPB + (t >> 6);   // one node per wave
  int c8 = t & 15;                       // channels c8*8 .. c8*8+7 ; head h = c8>>2
  int el = (t >> 4) & 3;                 // edge lane within wave
  int h = c8 >> 2;
  float o[8];
  #pragma unroll
  for (int k = 0; k < 8; ++k) o[k] = 0.f;
  if (n < Nn) {
    const u32* recEl = recE + (size_t)l * ((size_t)Ee * 2);
    int ph = h >> 1, sel = h & 1;
    float adh = ad_[n*NHD + h];
    int beg = rowp[n], end = rowp[n+1];
    float acc[8];
    #pragma unroll
    for (int k = 0; k < 8; ++k) acc[k] = 0.f;
    float wsum = 0.f;
    int i = beg + el;
    for (; i + 4 < end; i += 8) {
      // two edges in flight: i and i+4
      u32 eu0 = recEl[(size_t)i*2 + ph];
      u32 eu1 = recEl[(size_t)(i+4)*2 + ph];
      int s0 = (int)recS[i], s1 = (int)recS[i+4];
      float av0 = as_[s0*NHD + h], av1 = as_[s1*NHD + h];
      uint4 v0 = *(const uint4*)(xl2 + (size_t)s0 * 64 + c8*4);
      uint4 v1 = *(const uint4*)(xl2 + (size_t)s1 * 64 + c8*4);
      float a0 = (sel ? bfhi(eu0) : bflo(eu0)) + av0 + adh;
      a0 = (a0 > 0.f) ? a0 : SLOPE * a0;
      float w0 = __expf(a0);
      float a1 = (sel ? bfhi(eu1) : bflo(eu1)) + av1 + adh;
      a1 = (a1 > 0.f) ? a1 : SLOPE * a1;
      float w1 = __expf(a1);
      acc[0] += w0*bflo(v0.x); acc[1] += w0*bfhi(v0.x);
      acc[2] += w0*bflo(v0.y); acc[3] += w0*bfhi(v0.y);
      acc[4] += w0*bflo(v0.z); acc[5] += w0*bfhi(v0.z);
      acc[6] += w0*bflo(v0.w); acc[7] += w0*bfhi(v0.w);
      acc[0] += w1*bflo(v1.x); acc[1] += w1*bfhi(v1.x);
      acc[2] += w1*bflo(v1.y); acc[3] += w1*bfhi(v1.y);
      acc[4] += w1*bflo(v1.z); acc[5] += w1*bfhi(v1.z);
      acc[6] += w1*bflo(v1.w); acc[7] += w1*bfhi(v1.w);
      wsum += w0 + w1;
    }
    if (i < end) {
      u32 eu = recEl[(size_t)i*2 + ph];
      int s = (int)recS[i];
      float av = as_[s*NHD + h];
      uint4 v = *(const uint4*)(xl2 + (size_t)s * 64 + c8*4);
      float a = (sel ? bfhi(eu) : bflo(eu)) + av + adh;
      a = (a > 0.f) ? a : SLOPE * a;
      float wj = __expf(a);
      acc[0] += wj*bflo(v.x); acc[1] += wj*bfhi(v.x);
      acc[2] += wj*bflo(v.y); acc[3] += wj*bfhi(v.y);
      acc[4] += wj*bflo(v.z); acc[5] += wj*bfhi(v.z);
      acc[6] += wj*bflo(v.w); acc[7] += wj*bfhi(v.w);
      wsum += wj;
    }
    // combine edge-lanes (lanes L, L^16, L^32, L^48 share c8/head)
    #pragma unroll
    for (int k = 0; k < 8; ++k) {
      acc[k] += __shfl_xor(acc[k], 16);
      acc[k] += __shfl_xor(acc[k], 32);
    }
    wsum += __shfl_xor(wsum, 16);
    wsum += __shfl_xor(wsum, 32);
    if (el == 0) {
      float inv = 1.f / (wsum + 1e-16f);
      uint4 w0, w1;
      #pragma unroll
      for (int k = 0; k < 8; ++k) o[k] = acc[k]*inv + bias[c8*8 + k];
      w0.x = packsplit(o[0]); w0.y = packsplit(o[1]);
      w0.z = packsplit(o[2]); w0.w = packsplit(o[3]);
      w1.x = packsplit(o[4]); w1.y = packsplit(o[5]);
      w1.z = packsplit(o[6]); w1.w = packsplit(o[7]);
      uint4* op = (uint4*)(outp + (size_t)n * HC + c8*8);
      op[0] = w0; op[1] = w1;
    }
  }
  // o[] is zero for el!=0 threads and n>=Nn -> tree stays correct
  rsA[t] = make_float4(o[0], o[1], o[2], o[3]);
  rsB[t] = make_float4(o[4], o[5], o[6], o[7]);
  rqA[t] = make_float4(o[0]*o[0], o[1]*o[1], o[2]*o[2], o[3]*o[3]);
  rqB[t] = make_float4(o[4]*o[4], o[5]*o[5], o[6]*o[6], o[7]*o[7]);
  __syncthreads();
  for (int off = 256; off >= 16; off >>= 1) {
    if (t < off) {
      rsA[t].x += rsA[t+off].x; rsA[t].y += rsA[t+off].y;
      rsA[t].z += rsA[t+off].z; rsA[t].w += rsA[t+off].w;
      rsB[t].x += rsB[t+off].x; rsB[t].y += rsB[t+off].y;
      rsB[t].z += rsB[t+off].z; rsB[t].w += rsB[t+off].w;
      rqA[t].x += rqA[t+off].x; rqA[t].y += rqA[t+off].y;
      rqA[t].z += rqA[t+off].z; rqA[t].w += rqA[t+off].w;
      rqB[t].x += rqB[t+off].x; rqB[t].y += rqB[t+off].y;
      rqB[t].z += rqB[t+off].z; rqB[t].w += rqB[t+off].w;
    }
    __syncthreads();
  }
  if (t < 16) {
    float4* ps = (float4*)(psum + (size_t)blockIdx.x*HC + t*8);
    ps[0] = rsA[t]; ps[1] = rsB[t];
    float4* pq = (float4*)(psq + (size_t)blockIdx.x*HC + t*8);
    pq[0] = rqA[t]; pq[1] = rqB[t];
  }
}

// fused: column-sum of NBAG x 128 slots -> gsum/gsq atomics; LAST block
// finalizes scale/shift (coherent atomic reads) and re-zeroes for next layer.
__global__ __launch_bounds__(256) void k_bnpartfin(const float* __restrict__ psum, const float* __restrict__ psq,
                                                   float* __restrict__ gsum, float* __restrict__ gsq,
                                                   int* __restrict__ bnctr,
                                                   const float* __restrict__ gammaL, const float* __restrict__ betaL,
                                                   float* __restrict__ scb, float* __restrict__ shb)
{
  __shared__ float4 rs[256], rq[256];
  __shared__ int lastv;
  int t = threadIdx.x;
  int c4 = t & 31, rg = t >> 5;
  float4 s = make_float4(0.f,0.f,0.f,0.f), q = make_float4(0.f,0.f,0.f,0.f);
  for (int k = blockIdx.x*8 + rg; k < NBAG; k += 64*8) {
    float4 a = *(const float4*)(psum + (size_t)k*HC + c4*4);
    float4 b = *(const float4*)(psq  + (size_t)k*HC + c4*4);
    s.x += a.x; s.y += a.y; s.z += a.z; s.w += a.w;
    q.x += b.x; q.y += b.y; q.z += b.z; q.w += b.w;
  }
  rs[t] = s; rq[t] = q;
  __syncthreads();
  for (int off = 128; off >= 32; off >>= 1) {
    if (t < off) {
      rs[t].x += rs[t+off].x; rs[t].y += rs[t+off].y;
      rs[t].z += rs[t+off].z; rs[t].w += rs[t+off].w;
      rq[t].x += rq[t+off].x; rq[t].y += rq[t+off].y;
      rq[t].z += rq[t+off].z; rq[t].w += rq[t+off].w;
    }
    __syncthreads();
  }
  if (t < 32) {
    atomicAdd(&gsum[t*4+0], rs[t].x); atomicAdd(&gsum[t*4+1], rs[t].y);
    atomicAdd(&gsum[t*4+2], rs[t].z); atomicAdd(&gsum[t*4+3], rs[t].w);
    atomicAdd(&gsq[t*4+0], rq[t].x);  atomicAdd(&gsq[t*4+1], rq[t].y);
    atomicAdd(&gsq[t*4+2], rq[t].z);  atomicAdd(&gsq[t*4+3], rq[t].w);
  }
  __syncthreads();               // drain this block's atomics (barrier waits all mem ops)
  if (t == 0) {
    __threadfence();
    lastv = (atomicAdd(bnctr, 1) == 63);
  }
  __syncthreads();
  if (lastv) {
    if (t < HC) {
      float sv = atomicAdd(&gsum[t], 0.f);   // coherent read at LLC
      float qv = atomicAdd(&gsq[t], 0.f);
      float mu  = sv * (1.f / Nn);
      float var = qv * (1.f / Nn) - mu * mu;
      float sc = rsqrtf(var + BN_EPS) * gammaL[t];
      scb[t] = sc;                            // visible to next dispatch
      shb[t] = betaL[t] - mu * sc;
      atomicExch(&gsum[t], 0.f);              // coherent zero for next layer
      atomicExch(&gsq[t], 0.f);
    }
    if (t == 0) atomicExch(bnctr, 0);
  }
}

// mean-pool over packed input with final-layer BN+ReLU (scb/shb)
__global__ __launch_bounds__(256) void pool2(const u32* __restrict__ Ap, const int* __restrict__ gb,
                                             const float* __restrict__ scb, const float* __restrict__ shb,
                                             float* __restrict__ pool)
{
  __shared__ float4 red[256];
  int g = blockIdx.x >> 2, qt = blockIdx.x & 3;
  int t = threadIdx.x;
  int cg = t & 7;
  int rs = t >> 3;
  int c4 = qt*8 + cg;
  int c = c4 * 4;
  int lo = gb[g], hi = gb[g+1];
  float4 s4 = *(const float4*)(scb + c);
  float4 t4 = *(const float4*)(shb + c);
  float4 acc = make_float4(0.f,0.f,0.f,0.f);
  for (int n = lo + rs; n < hi; n += 32) {
    uint4 v = *(const uint4*)(Ap + (size_t)n*HC + c);
    acc.x += fmaxf((bflo(v.x)+bfhi(v.x))*s4.x + t4.x, 0.f);
    acc.y += fmaxf((bflo(v.y)+bfhi(v.y))*s4.y + t4.y, 0.f);
    acc.z += fmaxf((bflo(v.z)+bfhi(v.z))*s4.z + t4.z, 0.f);
    acc.w += fmaxf((bflo(v.w)+bfhi(v.w))*s4.w + t4.w, 0.f);
  }
  red[t] = acc;
  __syncthreads();
  for (int off = 128; off >= 8; off >>= 1) {
    if (t < off) {
      red[t].x += red[t+off].x; red[t].y += red[t+off].y;
      red[t].z += red[t+off].z; red[t].w += red[t+off].w;
    }
    __syncthreads();
  }
  if (t < 8) {
    float inv = 1.f / fmaxf((float)(hi - lo), 1.f);
    float4 r = red[t];
    r.x *= inv; r.y *= inv; r.z *= inv; r.w *= inv;
    *(float4*)(pool + (size_t)g*HC + qt*32 + t*4) = r;
  }
}

__global__ void final_fc(const float* __restrict__ pool,
                         const float* __restrict__ fcW, const float* __restrict__ fcb,
                         float* __restrict__ out)
{
  int t = blockIdx.x * 256 + threadIdx.x;
  if (t >= Gg * NOUT) return;
  int g = t >> 1, o = t & 1;
  float acc = 0.f;
  for (int k = 0; k < HC; ++k)
    acc += pool[(size_t)g * HC + k] * fcW[k * NOUT + o];
  out[t] = acc + fcb[o];
}

extern "C" void kernel_launch(void* const* d_in, const int* in_sizes, int n_in,
                              void* d_out, int out_size, void* d_ws, size_t ws_size,
                              hipStream_t stream)
{
  const float* x      = (const float*)d_in[0];
  const int*   eidx   = (const int*)d_in[1];
  const float* eattr  = (const float*)d_in[2];
  const int*   batch  = (const int*)d_in[3];
  const float* efcW   = (const float*)d_in[4];
  const float* efcb   = (const float*)d_in[5];
  const float* Wall   = (const float*)d_in[6];
  const float* attS   = (const float*)d_in[7];
  const float* attD   = (const float*)d_in[8];
  const float* attE   = (const float*)d_in[9];
  const float* linE   = (const float*)d_in[10];
  const float* biases = (const float*)d_in[11];
  const float* gamma  = (const float*)d_in[12];
  const float* beta   = (const float*)d_in[13];
  const float* fcW    = (const float*)d_in[14];
  const float* fcb    = (const float*)d_in[15];
  float* out = (float*)d_out;

  const int* src = eidx;
  const int* dst = eidx + Ee;

  float* ws    = (float*)d_ws;
  float* bufA  = ws;                            // N*128 packed u32 (layer outputs)
  float* bufB  = bufA + (size_t)Nn*HC;          // N*128 (u16 bf16 rows use half)
  float* as_   = bufB + (size_t)Nn*HC;          // N*4
  float* ad_   = as_ + (size_t)Nn*NHD;          // N*4
  float* Kmat  = ad_ + (size_t)Nn*NHD;          // 192
  float* kb    = Kmat + 192;                    // 16
  float* scb   = kb + 16;                       // 128
  float* shb   = scb + 128;                     // 128
  float* pool  = shb + 128;                     // G*128 (16B-aligned)
  u32*   rec   = (u32*)(pool + (size_t)Gg*HC);  // E*8 u32 region (SoA)
  u32*   recS  = rec;                           // E u32 (src ids, dst-sorted)
  u32*   recE  = rec + (size_t)Ee;              // 3 planes x E uint2 (ep pairs)
  u32*   Wf    = rec + (size_t)Ee*8;            // 3*128*128 u32
  float* psum  = (float*)(Wf + 3*HC*HC);        // NBAG*128
  float* psq   = psum + (size_t)NBAG*HC;        // NBAG*128
  int*   gb    = (int*)(psq + (size_t)NBAG*HC); // Gg+1
  int*   rowp  = gb + (Gg + 3);                 // N+1
  int*   deg   = rowp + (Nn + 1);               // N   <- memset region start
  int*   fill  = deg + Nn;                      // N
  float* gsum  = (float*)(fill + Nn);           // 128
  float* gsq   = gsum + 128;                    // 128
  int*   bnctr = (int*)(gsq + 128);             // 4 (one used)
  int*   bsum  = bnctr + 4;                     // NSB
  int*   bpre  = bsum + 128;                    // NSB
  // eord (E uint2 = 6.4 MB) aliases bufB (51.2 MB); dead before the first
  // gemm writes C2 into bufB.
  uint2* eord  = (uint2*)bufB;

  w_split<<<(3*HC*HC + 255)/256, 256, 0, stream>>>(Wall, Wf);
  compute_K<<<1, 512, 0, stream>>>(efcW, efcb, linE, attE, Kmat, kb, batch, gb);

  // one memset covers deg, fill, gsum, gsq, bnctr (contiguous)
  hipMemsetAsync(deg, 0, (size_t)(2*Nn + 260) * sizeof(int), stream);
  k_hist<<<(Ee + 255)/256, 256, 0, stream>>>(dst, deg);
  k_bsum<<<NSB, 256, 0, stream>>>(deg, bsum);
  k_mid<<<1, 128, 0, stream>>>(bsum, bpre, rowp);
  k_scan<<<NSB, 256, 0, stream>>>(deg, bpre, rowp);
  k_mkperm<<<(Ee + 255)/256, 256, 0, stream>>>(src, dst, rowp, fill, eord);
  k_fillpre2<<<(Ee + 63)/64, 256, 0, stream>>>(eord, eattr, Kmat, kb, recS, (uint2*)recE);

  for (int l = 0; l < 3; ++l) {
    const u32* A = (l == 0) ? (const u32*)x : (const u32*)bufA;
    gemm_mfma<<<(Nn + 63)/64, 256, 0, stream>>>(A, Wf + (size_t)l*HC*HC, (u16*)bufB,
                                                attS + l*HC, attD + l*HC, as_, ad_,
                                                scb, shb, (l > 0) ? 1 : 0);
    aggregate<<<NBAG, 512, 0, stream>>>(rowp, recS, recE, as_, ad_, l, (const u32*)bufB,
                                        biases + l*HC, (u32*)bufA, psum, psq);
    k_bnpartfin<<<64, 256, 0, stream>>>(psum, psq, gsum, gsq, bnctr,
                                        gamma + l*HC, beta + l*HC, scb, shb);
  }

  pool2<<<Gg*4, 256, 0, stream>>>((const u32*)bufA, gb, scb, shb, pool);
  final_fc<<<2, 256, 0, stream>>>(pool, fcW, fcb, out);
}

// Round 8
// 615.080 us; speedup vs baseline: 1.0588x; 1.0588x over previous
//
#include <hip/hip_runtime.h>

#define Nn 100000
#define Ee 800000
#define HC 128
#define HID 32
#define NHD 4
#define EDIM 16
#define Gg 256
#define NOUT 2
#define SLOPE 0.2f
#define BN_EPS 1e-5f
#define SCHUNK 1024
#define NSB 98    // ceil(Nn/SCHUNK)
#define NBAG 6250 // ceil(Nn/16) aggregate blocks / BN slots

typedef unsigned int u32;
typedef unsigned short u16;
typedef short v8s __attribute__((ext_vector_type(8)));
typedef float v4f __attribute__((ext_vector_type(4)));

union PkAB { u32 u[4]; v8s v; };

__device__ __forceinline__ float bflo(u32 u){ return __uint_as_float(u << 16); }
__device__ __forceinline__ float bfhi(u32 u){ return __uint_as_float(u & 0xFFFF0000u); }

__device__ __forceinline__ u32 bf16rne(float x)
{
  u32 b = __float_as_uint(x);
  return (b + 0x7FFFu + ((b >> 16) & 1u)) >> 16;
}
__device__ __forceinline__ u32 packsplit(float x)
{
  u32 hb = bf16rne(x);
  float hf = __uint_as_float(hb << 16);
  u32 lb = bf16rne(x - hf);
  return hb | (lb << 16);
}
__device__ __forceinline__ void split2(float f, u32& hb, u32& lb)
{
  hb = bf16rne(f);
  lb = bf16rne(f - __uint_as_float(hb << 16));
}

__device__ __forceinline__ int lbound(const int* __restrict__ a, int n, int key)
{
  int lo = 0, hi = n;
  while (lo < hi) {
    int mid = (lo + hi) >> 1;
    if (a[mid] < key) lo = mid + 1; else hi = mid;
  }
  return lo;
}

// ---- tiny weight precompute: Kmat[16][12], kb[12]; also graph-boundary gb ----
__global__ void compute_K(const float* __restrict__ efcW, const float* __restrict__ efcb,
                          const float* __restrict__ linE, const float* __restrict__ attE,
                          float* __restrict__ Kmat, float* __restrict__ kb,
                          const int* __restrict__ batch, int* __restrict__ gb)
{
  __shared__ float Msh[384];
  int t = threadIdx.x;
  if (t <= Gg) gb[t] = lbound(batch, Nn, t);   // independent of the rest
  if (t < 384) {
    int l = t >> 7, j = (t >> 2) & 31, h = t & 3;
    float m = 0.f;
    for (int c = 0; c < 32; ++c)
      m += linE[(l*32 + j)*128 + h*32 + c] * attE[(l*4 + h)*32 + c];
    Msh[l*128 + j*4 + h] = m;
  }
  __syncthreads();
  if (t < 192) {
    int k = t / 12, col = t % 12, l = col >> 2, h = col & 3;
    float acc = 0.f;
    for (int j = 0; j < 32; ++j)
      acc += efcW[k*32 + j] * Msh[l*128 + j*4 + h];
    Kmat[k*12 + col] = acc;
  } else if (t < 204) {
    int col = t - 192, l = col >> 2, h = col & 3;
    float acc = 0.f;
    for (int j = 0; j < 32; ++j)
      acc += efcb[j] * Msh[l*128 + j*4 + h];
    kb[col] = acc;
  }
}

// ---- W -> PRE-SWIZZLED split-bf16 MFMA B-fragments (once) ----
// Output u32 at ((((l*8+nt)*4+ks)*2+hl)*64+lane)*4+j holds the bf16 pair
// {P(k0,n), P(k0+1,n)} with k0 = ks*32 + (lane>>4)*8 + 2j, n = nt*16+(lane&15),
// P = hi-half (hl=0) or lo-residual (hl=1). gemm consumes these directly as
// MFMA operands — no per-iteration repack.
__global__ void w_split(const float* __restrict__ Wall, u32* __restrict__ Wf)
{
  int tid = blockIdx.x * 256 + threadIdx.x;
  if (tid >= 3*HC*HC) return;
  int l = tid / (HC*HC);
  int r = tid - l*HC*HC;
  int j = r & 3;
  int lane = (r >> 2) & 63;
  int hl = (r >> 8) & 1;
  int ks = (r >> 9) & 3;
  int nt = (r >> 11) & 7;
  int q = lane >> 4, col = lane & 15;
  int n = nt*16 + col;
  int k0 = ks*32 + q*8 + 2*j;
  const float* Wl = Wall + (size_t)l*HC*HC;
  float w0 = Wl[(size_t)k0*HC + n];
  float w1 = Wl[(size_t)(k0+1)*HC + n];
  u32 p0, p1;
  if (hl == 0) {
    p0 = bf16rne(w0);
    p1 = bf16rne(w1);
  } else {
    u32 h0 = bf16rne(w0); p0 = bf16rne(w0 - __uint_as_float(h0 << 16));
    u32 h1 = bf16rne(w1); p1 = bf16rne(w1 - __uint_as_float(h1 << 16));
  }
  Wf[tid] = p0 | (p1 << 16);
}

// ---- CSR build ----
__global__ void k_hist(const int* __restrict__ dst, int* __restrict__ deg)
{
  int e = blockIdx.x * 256 + threadIdx.x;
  if (e < Ee) atomicAdd(&deg[dst[e]], 1);
}

__global__ void k_bsum(const int* __restrict__ deg, int* __restrict__ bsum)
{
  __shared__ int sh[256];
  int b = blockIdx.x, t = threadIdx.x;
  int s = 0;
  for (int i = t; i < SCHUNK; i += 256) {
    int idx = b*SCHUNK + i;
    if (idx < Nn) s += deg[idx];
  }
  sh[t] = s; __syncthreads();
  for (int o = 128; o; o >>= 1) { if (t < o) sh[t] += sh[t+o]; __syncthreads(); }
  if (!t) bsum[b] = sh[0];
}

__global__ void k_mid(const int* __restrict__ bsum, int* __restrict__ bpre, int* __restrict__ rowp)
{
  __shared__ int sh[NSB];
  int t = threadIdx.x;
  if (t < NSB) sh[t] = bsum[t];
  __syncthreads();
  if (!t) {
    int run = 0;
    for (int i = 0; i < NSB; ++i) { int v = sh[i]; sh[i] = run; run += v; }
    rowp[Nn] = run;
  }
  __syncthreads();
  if (t < NSB) bpre[t] = sh[t];
}

__global__ void k_scan(const int* __restrict__ deg, const int* __restrict__ bpre, int* __restrict__ rowp)
{
  __shared__ int sh[SCHUNK];
  int b = blockIdx.x, t = threadIdx.x;
  for (int i = t; i < SCHUNK; i += 256) {
    int idx = b*SCHUNK + i;
    sh[i] = (idx < Nn) ? deg[idx] : 0;
  }
  __syncthreads();
  if (!t) {
    int run = 0;
    for (int i = 0; i < SCHUNK; ++i) { int v = sh[i]; sh[i] = run; run += v; }
  }
  __syncthreads();
  int base = bpre[b];
  for (int i = t; i < SCHUNK; i += 256) {
    int idx = b*SCHUNK + i;
    if (idx < Nn) rowp[idx] = sh[i] + base;
  }
}

// scatter only an 8-byte {edge id, src} pair to the dst-sorted position.
__global__ void k_mkperm(const int* __restrict__ src, const int* __restrict__ dst,
                         const int* __restrict__ rowp, int* __restrict__ fill,
                         uint2* __restrict__ eord)
{
  int e = blockIdx.x * 256 + threadIdx.x;
  if (e >= Ee) return;
  int d = dst[e];
  int pos = rowp[d] + atomicAdd(&fill[d], 1);
  eord[pos] = make_uint2((u32)e, (u32)src[e]);
}

// QUAD-COOPERATIVE edge precompute: 4 lanes per edge read the 64-B eattr
// line coalesced; shfl-reduce the 16x12 matvec; lanes write SoA planes
// coalesced. recS[pos]=src ; recE[l][pos] = uint2{ep0|ep1<<16, ep2|ep3<<16}.
__global__ __launch_bounds__(256) void k_fillpre2(const uint2* __restrict__ eord,
                           const float* __restrict__ eattr,
                           const float* __restrict__ Kmat, const float* __restrict__ kb,
                           u32* __restrict__ recS, uint2* __restrict__ recE)
{
  int t = threadIdx.x;
  int qg = t >> 2, r = t & 3;
  int pos = blockIdx.x * 64 + qg;
  if (pos >= Ee) return;
  uint2 es = eord[pos];           // broadcast within quad
  int e = (int)es.x;
  float4 ea = *(const float4*)(eattr + (size_t)e * EDIM + r*4);  // quad covers one 64B line
  float part[12];
  #pragma unroll
  for (int col = 0; col < 12; ++col) {
    part[col] = ea.x * Kmat[(r*4+0)*12 + col]
              + ea.y * Kmat[(r*4+1)*12 + col]
              + ea.z * Kmat[(r*4+2)*12 + col]
              + ea.w * Kmat[(r*4+3)*12 + col];
  }
  #pragma unroll
  for (int col = 0; col < 12; ++col) {
    part[col] += __shfl_xor(part[col], 1);
    part[col] += __shfl_xor(part[col], 2);
    part[col] += kb[col];
  }
  if (r < 3) {
    uint2 w;
    w.x = bf16rne(part[4*r+0]) | (bf16rne(part[4*r+1]) << 16);
    w.y = bf16rne(part[4*r+2]) | (bf16rne(part[4*r+3]) << 16);
    recE[(size_t)r*Ee + pos] = w;
  } else {
    recS[pos] = es.y;
  }
}

// ---- MFMA GEMM, 64-row blocks; B ks-slice staged in 16 KB LDS (pre-swizzled
// Bh/Bl fragments — no repack in the inner loop);
// mode 0: A = raw fp32 x rows; mode 1: packed split-bf16 + BN+ReLU at A-load.
// C as bf16; attn dots fused; as_/ad_ node-major.
__global__ __launch_bounds__(256, 4) void gemm_mfma(const u32* __restrict__ Apk,
                                                    const u32* __restrict__ Wf,
                                                    u16* __restrict__ C2,
                                                    const float* __restrict__ aS,
                                                    const float* __restrict__ aD,
                                                    float* __restrict__ as_,
                                                    float* __restrict__ ad_,
                                                    const float* __restrict__ scb,
                                                    const float* __restrict__ shb,
                                                    int mode)
{
  __shared__ uint4 Bsh[1024];   // 16 KB: [nt(8)][hl(2)][lane(64)]
  int t = threadIdx.x;
  int w = t >> 6, lane = t & 63;
  int col = lane & 15, q = lane >> 4;
  int rbase = blockIdx.x * 64 + w * 16;

  v4f acc[8];
  #pragma unroll
  for (int nt = 0; nt < 8; ++nt) acc[nt] = (v4f){0.f, 0.f, 0.f, 0.f};

  const uint4* Wf4 = (const uint4*)Wf;

  int ar = rbase + col;
  if (ar >= Nn) ar = Nn - 1;
  const uint4* pa = (const uint4*)(Apk + (size_t)ar*HC);
  uint4 ra[8];
  #pragma unroll
  for (int ks = 0; ks < 4; ++ks) {
    ra[2*ks]   = pa[ks*8 + q*2];
    ra[2*ks+1] = pa[ks*8 + q*2 + 1];
  }

  for (int ks = 0; ks < 4; ++ks) {
    // stage B ks-slice: 1024 uint4 (8 nt x 2 hl x 64 lane)
    #pragma unroll
    for (int i = 0; i < 4; ++i) {
      int u = t + i*256;
      int nt = u >> 7, rem = u & 127;
      Bsh[u] = Wf4[((nt*4 + ks)*2 + (rem >> 6))*64 + (rem & 63)];
    }
    __syncthreads();

    PkAB Ah, Al;
    int cb = ks*32 + q*8;
    uint4 r0 = ra[2*ks], r1 = ra[2*ks+1];
    float f0, f1, f2, f3, f4, f5, f6, f7;
    if (mode == 0) {
      // raw fp32 x: uint4 lanes are float bits
      f0 = __uint_as_float(r0.x); f1 = __uint_as_float(r0.y);
      f2 = __uint_as_float(r0.z); f3 = __uint_as_float(r0.w);
      f4 = __uint_as_float(r1.x); f5 = __uint_as_float(r1.y);
      f6 = __uint_as_float(r1.z); f7 = __uint_as_float(r1.w);
    } else {
      float4 sc0 = *(const float4*)(scb + cb), sc1 = *(const float4*)(scb + cb + 4);
      float4 sh0 = *(const float4*)(shb + cb), sh1 = *(const float4*)(shb + cb + 4);
      f0 = fmaxf((bflo(r0.x)+bfhi(r0.x))*sc0.x + sh0.x, 0.f);
      f1 = fmaxf((bflo(r0.y)+bfhi(r0.y))*sc0.y + sh0.y, 0.f);
      f2 = fmaxf((bflo(r0.z)+bfhi(r0.z))*sc0.z + sh0.z, 0.f);
      f3 = fmaxf((bflo(r0.w)+bfhi(r0.w))*sc0.w + sh0.w, 0.f);
      f4 = fmaxf((bflo(r1.x)+bfhi(r1.x))*sc1.x + sh1.x, 0.f);
      f5 = fmaxf((bflo(r1.y)+bfhi(r1.y))*sc1.y + sh1.y, 0.f);
      f6 = fmaxf((bflo(r1.z)+bfhi(r1.z))*sc1.z + sh1.z, 0.f);
      f7 = fmaxf((bflo(r1.w)+bfhi(r1.w))*sc1.w + sh1.w, 0.f);
    }
    {
      u32 hb0,lb0,hb1,lb1,hb2,lb2,hb3,lb3,hb4,lb4,hb5,lb5,hb6,lb6,hb7,lb7;
      split2(f0,hb0,lb0); split2(f1,hb1,lb1); split2(f2,hb2,lb2); split2(f3,hb3,lb3);
      split2(f4,hb4,lb4); split2(f5,hb5,lb5); split2(f6,hb6,lb6); split2(f7,hb7,lb7);
      Ah.u[0] = hb0 | (hb1 << 16);  Al.u[0] = lb0 | (lb1 << 16);
      Ah.u[1] = hb2 | (hb3 << 16);  Al.u[1] = lb2 | (lb3 << 16);
      Ah.u[2] = hb4 | (hb5 << 16);  Al.u[2] = lb4 | (lb5 << 16);
      Ah.u[3] = hb6 | (hb7 << 16);  Al.u[3] = lb6 | (lb7 << 16);
    }
    #pragma unroll
    for (int nt = 0; nt < 8; ++nt) {
      uint4 b0 = Bsh[nt*128 + lane];        // pre-swizzled Bh
      uint4 b1 = Bsh[nt*128 + 64 + lane];   // pre-swizzled Bl
      PkAB Bh, Bl;
      Bh.u[0] = b0.x; Bh.u[1] = b0.y; Bh.u[2] = b0.z; Bh.u[3] = b0.w;
      Bl.u[0] = b1.x; Bl.u[1] = b1.y; Bl.u[2] = b1.z; Bl.u[3] = b1.w;
      acc[nt] = __builtin_amdgcn_mfma_f32_16x16x32_bf16(Ah.v, Bh.v, acc[nt], 0, 0, 0);
      acc[nt] = __builtin_amdgcn_mfma_f32_16x16x32_bf16(Ah.v, Bl.v, acc[nt], 0, 0, 0);
      acc[nt] = __builtin_amdgcn_mfma_f32_16x16x32_bf16(Al.v, Bh.v, acc[nt], 0, 0, 0);
    }
    __syncthreads();
  }

  #pragma unroll
  for (int reg = 0; reg < 4; ++reg) {
    int row = rbase + q*4 + reg;
    if (row < Nn) {
      #pragma unroll
      for (int nt = 0; nt < 8; ++nt)
        C2[(size_t)row*HC + nt*16 + col] = (u16)bf16rne(acc[nt][reg]);
    }
  }

  #pragma unroll
  for (int h = 0; h < 4; ++h) {
    float a0 = aS[32*h + col], a1 = aS[32*h + 16 + col];
    float d0 = aD[32*h + col], d1 = aD[32*h + 16 + col];
    #pragma unroll
    for (int reg = 0; reg < 4; ++reg) {
      float s1 = acc[2*h][reg]*a0 + acc[2*h+1][reg]*a1;
      float s2 = acc[2*h][reg]*d0 + acc[2*h+1][reg]*d1;
      s1 += __shfl_xor(s1, 1); s1 += __shfl_xor(s1, 2);
      s1 += __shfl_xor(s1, 4); s1 += __shfl_xor(s1, 8);
      s2 += __shfl_xor(s2, 1); s2 += __shfl_xor(s2, 2);
      s2 += __shfl_xor(s2, 4); s2 += __shfl_xor(s2, 8);
      if (col == 0) {
        int row = rbase + q*4 + reg;
        if (row < Nn) {
          as_[row*NHD + h] = s1;
          ad_[row*NHD + h] = s2;
        }
      }
    }
  }
}

// CSR aggregation, 16 thr/node (uint4 gathers), 16 nodes/block;
// fused alpha->leaky->exp; packed output; per-block BN partial slot.
// NOTE: no launch_bounds min-wave clamp — the 8-deep gather batch needs
// ~52 VGPRs; clamping to 32 serializes the gathers (R1/R5 regressions).
__global__ __launch_bounds__(256) void aggregate(const int* __restrict__ rowp,
                                                 const u32* __restrict__ recS,
                                                 const u32* __restrict__ recE,
                                                 const float* __restrict__ as_, const float* __restrict__ ad_,
                                                 int l, const u32* __restrict__ xl2,
                                                 const float* __restrict__ bias, u32* __restrict__ outp,
                                                 float* __restrict__ psum, float* __restrict__ psq)
{
  __shared__ float4 rsA[256], rsB[256], rqA[256], rqB[256];
  int t = threadIdx.x;
  int n = blockIdx.x * 16 + (t >> 4);
  int c8 = t & 15;                  // channels c8*8 .. c8*8+7 ; head h = c8>>2
  int h = c8 >> 2;
  float o[8];
  #pragma unroll
  for (int k = 0; k < 8; ++k) o[k] = 0.f;
  if (n < Nn) {
    const u32* recEl = recE + (size_t)l * ((size_t)Ee * 2);
    int ph = h >> 1, sel = h & 1;
    float adh = ad_[n*NHD + h];
    int beg = rowp[n], end = rowp[n+1];
    float acc[8];
    #pragma unroll
    for (int k = 0; k < 8; ++k) acc[k] = 0.f;
    float wsum = 0.f;
    int i = beg;
    for (; i + 8 <= end; i += 8) {
      u32 eu[8]; int s[8]; float av[8]; uint4 v[8];
      #pragma unroll
      for (int j = 0; j < 8; ++j) eu[j] = recEl[(size_t)(i+j)*2 + ph];
      #pragma unroll
      for (int j = 0; j < 8; ++j) s[j] = (int)recS[i+j];
      #pragma unroll
      for (int j = 0; j < 8; ++j) av[j] = as_[s[j]*NHD + h];
      #pragma unroll
      for (int j = 0; j < 8; ++j) v[j] = *(const uint4*)(xl2 + (size_t)s[j] * 64 + c8*4);
      #pragma unroll
      for (int j = 0; j < 8; ++j) {
        float ep = sel ? bfhi(eu[j]) : bflo(eu[j]);
        float a = ep + av[j] + adh;
        a = (a > 0.f) ? a : SLOPE * a;
        float wj = __expf(a);
        acc[0] += wj*bflo(v[j].x); acc[1] += wj*bfhi(v[j].x);
        acc[2] += wj*bflo(v[j].y); acc[3] += wj*bfhi(v[j].y);
        acc[4] += wj*bflo(v[j].z); acc[5] += wj*bfhi(v[j].z);
        acc[6] += wj*bflo(v[j].w); acc[7] += wj*bfhi(v[j].w);
        wsum += wj;
      }
    }
    for (; i + 4 <= end; i += 4) {
      u32 eu[4]; int s[4]; float av[4]; uint4 v[4];
      #pragma unroll
      for (int j = 0; j < 4; ++j) eu[j] = recEl[(size_t)(i+j)*2 + ph];
      #pragma unroll
      for (int j = 0; j < 4; ++j) s[j] = (int)recS[i+j];
      #pragma unroll
      for (int j = 0; j < 4; ++j) av[j] = as_[s[j]*NHD + h];
      #pragma unroll
      for (int j = 0; j < 4; ++j) v[j] = *(const uint4*)(xl2 + (size_t)s[j] * 64 + c8*4);
      #pragma unroll
      for (int j = 0; j < 4; ++j) {
        float ep = sel ? bfhi(eu[j]) : bflo(eu[j]);
        float a = ep + av[j] + adh;
        a = (a > 0.f) ? a : SLOPE * a;
        float wj = __expf(a);
        acc[0] += wj*bflo(v[j].x); acc[1] += wj*bfhi(v[j].x);
        acc[2] += wj*bflo(v[j].y); acc[3] += wj*bfhi(v[j].y);
        acc[4] += wj*bflo(v[j].z); acc[5] += wj*bfhi(v[j].z);
        acc[6] += wj*bflo(v[j].w); acc[7] += wj*bfhi(v[j].w);
        wsum += wj;
      }
    }
    for (; i < end; ++i) {
      u32 eu = recEl[(size_t)i*2 + ph];
      int s = (int)recS[i];
      float ep = sel ? bfhi(eu) : bflo(eu);
      float a = ep + as_[s*NHD + h] + adh;
      a = (a > 0.f) ? a : SLOPE * a;
      float wj = __expf(a);
      uint4 v = *(const uint4*)(xl2 + (size_t)s * 64 + c8*4);
      acc[0] += wj*bflo(v.x); acc[1] += wj*bfhi(v.x);
      acc[2] += wj*bflo(v.y); acc[3] += wj*bfhi(v.y);
      acc[4] += wj*bflo(v.z); acc[5] += wj*bfhi(v.z);
      acc[6] += wj*bflo(v.w); acc[7] += wj*bfhi(v.w);
      wsum += wj;
    }
    float inv = 1.f / (wsum + 1e-16f);
    uint4 w0, w1;
    #pragma unroll
    for (int k = 0; k < 8; ++k) o[k] = acc[k]*inv + bias[c8*8 + k];
    w0.x = packsplit(o[0]); w0.y = packsplit(o[1]);
    w0.z = packsplit(o[2]); w0.w = packsplit(o[3]);
    w1.x = packsplit(o[4]); w1.y = packsplit(o[5]);
    w1.z = packsplit(o[6]); w1.w = packsplit(o[7]);
    uint4* op = (uint4*)(outp + (size_t)n * HC + c8*8);
    op[0] = w0; op[1] = w1;
  }
  rsA[t] = make_float4(o[0], o[1], o[2], o[3]);
  rsB[t] = make_float4(o[4], o[5], o[6], o[7]);
  rqA[t] = make_float4(o[0]*o[0], o[1]*o[1], o[2]*o[2], o[3]*o[3]);
  rqB[t] = make_float4(o[4]*o[4], o[5]*o[5], o[6]*o[6], o[7]*o[7]);
  __syncthreads();
  for (int off = 128; off >= 16; off >>= 1) {
    if (t < off) {
      rsA[t].x += rsA[t+off].x; rsA[t].y += rsA[t+off].y;
      rsA[t].z += rsA[t+off].z; rsA[t].w += rsA[t+off].w;
      rsB[t].x += rsB[t+off].x; rsB[t].y += rsB[t+off].y;
      rsB[t].z += rsB[t+off].z; rsB[t].w += rsB[t+off].w;
      rqA[t].x += rqA[t+off].x; rqA[t].y += rqA[t+off].y;
      rqA[t].z += rqA[t+off].z; rqA[t].w += rqA[t+off].w;
      rqB[t].x += rqB[t+off].x; rqB[t].y += rqB[t+off].y;
      rqB[t].z += rqB[t+off].z; rqB[t].w += rqB[t+off].w;
    }
    __syncthreads();
  }
  if (t < 16) {
    float4* ps = (float4*)(psum + (size_t)blockIdx.x*HC + t*8);
    ps[0] = rsA[t]; ps[1] = rsB[t];
    float4* pq = (float4*)(psq + (size_t)blockIdx.x*HC + t*8);
    pq[0] = rqA[t]; pq[1] = rqB[t];
  }
}

// fused: column-sum of NBAG x 128 slots -> gsum/gsq atomics; LAST block
// finalizes scale/shift (coherent atomic reads) and re-zeroes for next layer.
__global__ __launch_bounds__(256) void k_bnpartfin(const float* __restrict__ psum, const float* __restrict__ psq,
                                                   float* __restrict__ gsum, float* __restrict__ gsq,
                                                   int* __restrict__ bnctr,
                                                   const float* __restrict__ gammaL, const float* __restrict__ betaL,
                                                   float* __restrict__ scb, float* __restrict__ shb)
{
  __shared__ float4 rs[256], rq[256];
  __shared__ int lastv;
  int t = threadIdx.x;
  int c4 = t & 31, rg = t >> 5;
  float4 s = make_float4(0.f,0.f,0.f,0.f), q = make_float4(0.f,0.f,0.f,0.f);
  for (int k = blockIdx.x*8 + rg; k < NBAG; k += 64*8) {
    float4 a = *(const float4*)(psum + (size_t)k*HC + c4*4);
    float4 b = *(const float4*)(psq  + (size_t)k*HC + c4*4);
    s.x += a.x; s.y += a.y; s.z += a.z; s.w += a.w;
    q.x += b.x; q.y += b.y; q.z += b.z; q.w += b.w;
  }
  rs[t] = s; rq[t] = q;
  __syncthreads();
  for (int off = 128; off >= 32; off >>= 1) {
    if (t < off) {
      rs[t].x += rs[t+off].x; rs[t].y += rs[t+off].y;
      rs[t].z += rs[t+off].z; rs[t].w += rs[t+off].w;
      rq[t].x += rq[t+off].x; rq[t].y += rq[t+off].y;
      rq[t].z += rq[t+off].z; rq[t].w += rq[t+off].w;
    }
    __syncthreads();
  }
  if (t < 32) {
    atomicAdd(&gsum[t*4+0], rs[t].x); atomicAdd(&gsum[t*4+1], rs[t].y);
    atomicAdd(&gsum[t*4+2], rs[t].z); atomicAdd(&gsum[t*4+3], rs[t].w);
    atomicAdd(&gsq[t*4+0], rq[t].x);  atomicAdd(&gsq[t*4+1], rq[t].y);
    atomicAdd(&gsq[t*4+2], rq[t].z);  atomicAdd(&gsq[t*4+3], rq[t].w);
  }
  __syncthreads();               // drain this block's atomics (barrier waits all mem ops)
  if (t == 0) {
    __threadfence();
    lastv = (atomicAdd(bnctr, 1) == 63);
  }
  __syncthreads();
  if (lastv) {
    if (t < HC) {
      float sv = atomicAdd(&gsum[t], 0.f);   // coherent read at LLC
      float qv = atomicAdd(&gsq[t], 0.f);
      float mu  = sv * (1.f / Nn);
      float var = qv * (1.f / Nn) - mu * mu;
      float sc = rsqrtf(var + BN_EPS) * gammaL[t];
      scb[t] = sc;                            // visible to next dispatch
      shb[t] = betaL[t] - mu * sc;
      atomicExch(&gsum[t], 0.f);              // coherent zero for next layer
      atomicExch(&gsq[t], 0.f);
    }
    if (t == 0) atomicExch(bnctr, 0);
  }
}

// mean-pool over packed input with final-layer BN+ReLU (scb/shb)
__global__ __launch_bounds__(256) void pool2(const u32* __restrict__ Ap, const int* __restrict__ gb,
                                             const float* __restrict__ scb, const float* __restrict__ shb,
                                             float* __restrict__ pool)
{
  __shared__ float4 red[256];
  int g = blockIdx.x >> 2, qt = blockIdx.x & 3;
  int t = threadIdx.x;
  int cg = t & 7;
  int rs = t >> 3;
  int c4 = qt*8 + cg;
  int c = c4 * 4;
  int lo = gb[g], hi = gb[g+1];
  float4 s4 = *(const float4*)(scb + c);
  float4 t4 = *(const float4*)(shb + c);
  float4 acc = make_float4(0.f,0.f,0.f,0.f);
  for (int n = lo + rs; n < hi; n += 32) {
    uint4 v = *(const uint4*)(Ap + (size_t)n*HC + c);
    acc.x += fmaxf((bflo(v.x)+bfhi(v.x))*s4.x + t4.x, 0.f);
    acc.y += fmaxf((bflo(v.y)+bfhi(v.y))*s4.y + t4.y, 0.f);
    acc.z += fmaxf((bflo(v.z)+bfhi(v.z))*s4.z + t4.z, 0.f);
    acc.w += fmaxf((bflo(v.w)+bfhi(v.w))*s4.w + t4.w, 0.f);
  }
  red[t] = acc;
  __syncthreads();
  for (int off = 128; off >= 8; off >>= 1) {
    if (t < off) {
      red[t].x += red[t+off].x; red[t].y += red[t+off].y;
      red[t].z += red[t+off].z; red[t].w += red[t+off].w;
    }
    __syncthreads();
  }
  if (t < 8) {
    float inv = 1.f / fmaxf((float)(hi - lo), 1.f);
    float4 r = red[t];
    r.x *= inv; r.y *= inv; r.z *= inv; r.w *= inv;
    *(float4*)(pool + (size_t)g*HC + qt*32 + t*4) = r;
  }
}

__global__ void final_fc(const float* __restrict__ pool,
                         const float* __restrict__ fcW, const float* __restrict__ fcb,
                         float* __restrict__ out)
{
  int t = blockIdx.x * 256 + threadIdx.x;
  if (t >= Gg * NOUT) return;
  int g = t >> 1, o = t & 1;
  float acc = 0.f;
  for (int k = 0; k < HC; ++k)
    acc += pool[(size_t)g * HC + k] * fcW[k * NOUT + o];
  out[t] = acc + fcb[o];
}

extern "C" void kernel_launch(void* const* d_in, const int* in_sizes, int n_in,
                              void* d_out, int out_size, void* d_ws, size_t ws_size,
                              hipStream_t stream)
{
  const float* x      = (const float*)d_in[0];
  const int*   eidx   = (const int*)d_in[1];
  const float* eattr  = (const float*)d_in[2];
  const int*   batch  = (const int*)d_in[3];
  const float* efcW   = (const float*)d_in[4];
  const float* efcb   = (const float*)d_in[5];
  const float* Wall   = (const float*)d_in[6];
  const float* attS   = (const float*)d_in[7];
  const float* attD   = (const float*)d_in[8];
  const float* attE   = (const float*)d_in[9];
  const float* linE   = (const float*)d_in[10];
  const float* biases = (const float*)d_in[11];
  const float* gamma  = (const float*)d_in[12];
  const float* beta   = (const float*)d_in[13];
  const float* fcW    = (const float*)d_in[14];
  const float* fcb    = (const float*)d_in[15];
  float* out = (float*)d_out;

  const int* src = eidx;
  const int* dst = eidx + Ee;

  float* ws    = (float*)d_ws;
  float* bufA  = ws;                            // N*128 packed u32 (layer outputs)
  float* bufB  = bufA + (size_t)Nn*HC;          // N*128 (u16 bf16 rows use half)
  float* as_   = bufB + (size_t)Nn*HC;          // N*4
  float* ad_   = as_ + (size_t)Nn*NHD;          // N*4
  float* Kmat  = ad_ + (size_t)Nn*NHD;          // 192
  float* kb    = Kmat + 192;                    // 16
  float* scb   = kb + 16;                       // 128
  float* shb   = scb + 128;                     // 128
  float* pool  = shb + 128;                     // G*128 (16B-aligned)
  u32*   rec   = (u32*)(pool + (size_t)Gg*HC);  // E*8 u32 region (SoA)
  u32*   recS  = rec;                           // E u32 (src ids, dst-sorted)
  u32*   recE  = rec + (size_t)Ee;              // 3 planes x E uint2 (ep pairs)
  u32*   Wf    = rec + (size_t)Ee*8;            // 3*128*128 u32
  float* psum  = (float*)(Wf + 3*HC*HC);        // NBAG*128
  float* psq   = psum + (size_t)NBAG*HC;        // NBAG*128
  int*   gb    = (int*)(psq + (size_t)NBAG*HC); // Gg+1
  int*   rowp  = gb + (Gg + 3);                 // N+1
  int*   deg   = rowp + (Nn + 1);               // N   <- memset region start
  int*   fill  = deg + Nn;                      // N
  float* gsum  = (float*)(fill + Nn);           // 128
  float* gsq   = gsum + 128;                    // 128
  int*   bnctr = (int*)(gsq + 128);             // 4 (one used)
  int*   bsum  = bnctr + 4;                     // NSB
  int*   bpre  = bsum + 128;                    // NSB
  // eord (E uint2 = 6.4 MB) aliases bufB (51.2 MB); dead before the first
  // gemm writes C2 into bufB.
  uint2* eord  = (uint2*)bufB;

  w_split<<<(3*HC*HC + 255)/256, 256, 0, stream>>>(Wall, Wf);
  compute_K<<<1, 512, 0, stream>>>(efcW, efcb, linE, attE, Kmat, kb, batch, gb);

  // one memset covers deg, fill, gsum, gsq, bnctr (contiguous)
  hipMemsetAsync(deg, 0, (size_t)(2*Nn + 260) * sizeof(int), stream);
  k_hist<<<(Ee + 255)/256, 256, 0, stream>>>(dst, deg);
  k_bsum<<<NSB, 256, 0, stream>>>(deg, bsum);
  k_mid<<<1, 128, 0, stream>>>(bsum, bpre, rowp);
  k_scan<<<NSB, 256, 0, stream>>>(deg, bpre, rowp);
  k_mkperm<<<(Ee + 255)/256, 256, 0, stream>>>(src, dst, rowp, fill, eord);
  k_fillpre2<<<(Ee + 63)/64, 256, 0, stream>>>(eord, eattr, Kmat, kb, recS, (uint2*)recE);

  for (int l = 0; l < 3; ++l) {
    const u32* A = (l == 0) ? (const u32*)x : (const u32*)bufA;
    gemm_mfma<<<(Nn + 63)/64, 256, 0, stream>>>(A, Wf + (size_t)l*HC*HC, (u16*)bufB,
                                                attS + l*HC, attD + l*HC, as_, ad_,
                                                scb, shb, (l > 0) ? 1 : 0);
    aggregate<<<NBAG, 256, 0, stream>>>(rowp, recS, recE, as_, ad_, l, (const u32*)bufB,
                                        biases + l*HC, (u32*)bufA, psum, psq);
    k_bnpartfin<<<64, 256, 0, stream>>>(psum, psq, gsum, gsq, bnctr,
                                        gamma + l*HC, beta + l*HC, scb, shb);
  }

  pool2<<<Gg*4, 256, 0, stream>>>((const u32*)bufA, gb, scb, shb, pool);
  final_fc<<<2, 256, 0, stream>>>(pool, fcW, fcb, out);
}